// Round 3
// baseline (1255.577 us; speedup 1.0000x reference)
//
#include <hip/hip_runtime.h>

// LDPC sum-product BP decode, (3,6)-regular, N=8192, R=4096, B=1024, 10 iters.
// State kept across half-iterations: c2v [E,B] and tot [N,B] (v2c = tot[var]-c2v).
// All big arrays are B-contiguous so each node/edge row is a coalesced 4KB read.
//
// R2 fixes:
//  - NaN hazard: reference computes prod(tanh)/t_i which is 0/0 when t_i==0
//    (exact f32 cancellation in v2c — happens at ulp-reordering mercy).
//    Replaced with division-free prefix/suffix leave-one-out products.
//  - Determinism: atomic slot assignment is erased by a 12-comparator sorting
//    network per check row -> bit-identical table -> graph replay tripwire OK.

#define N_  8192
#define R_  4096
#define DV_ 3
#define DC_ 6
#define E_  (N_ * DV_)
#define B_  1024
#define ITERS_ 10

__device__ __forceinline__ float clip999(float x) {
  if (x > 0.999f) return 0.999f;
  if (x < -0.999f) return -0.999f;
  return x;
}

// Pass 1: scatter edges into per-check rows (slot order nondeterministic).
__global__ __launch_bounds__(256) void build_edges_kernel(
    const int* __restrict__ edge_check, int* __restrict__ counters,
    int* __restrict__ check_edges) {
  int e = blockIdx.x * 256 + threadIdx.x;
  if (e < E_) {
    int r = edge_check[e];
    int s = atomicAdd(&counters[r], 1);
    check_edges[r * DC_ + s] = e;
  }
}

// Pass 2: sort each 6-entry row ascending (optimal 12-comparator network).
// Makes the table deterministic regardless of atomic scheduling.
__global__ __launch_bounds__(256) void sort_edges_kernel(
    int* __restrict__ check_edges) {
  int r = blockIdx.x * 256 + threadIdx.x;
  if (r >= R_) return;
  int e0 = check_edges[r * DC_ + 0], e1 = check_edges[r * DC_ + 1];
  int e2 = check_edges[r * DC_ + 2], e3 = check_edges[r * DC_ + 3];
  int e4 = check_edges[r * DC_ + 4], e5 = check_edges[r * DC_ + 5];
#define CSWAP(a, b) { int lo = min(a, b), hi = max(a, b); a = lo; b = hi; }
  CSWAP(e0, e5) CSWAP(e1, e3) CSWAP(e2, e4)
  CSWAP(e1, e2) CSWAP(e3, e4)
  CSWAP(e0, e3) CSWAP(e2, e5)
  CSWAP(e0, e1) CSWAP(e2, e3) CSWAP(e4, e5)
  CSWAP(e1, e2) CSWAP(e3, e4)
#undef CSWAP
  check_edges[r * DC_ + 0] = e0; check_edges[r * DC_ + 1] = e1;
  check_edges[r * DC_ + 2] = e2; check_edges[r * DC_ + 3] = e3;
  check_edges[r * DC_ + 4] = e4; check_edges[r * DC_ + 5] = e5;
}

// llr_t[n][b] = 2 * received[b][n]   (tiled transpose, 32x32)
__global__ __launch_bounds__(256) void transpose_llr_kernel(
    const float* __restrict__ recv, float* __restrict__ llr_t) {
  __shared__ float tile[32][33];
  int n0 = blockIdx.x * 32;
  int b0 = blockIdx.y * 32;
  int tx = threadIdx.x, ty = threadIdx.y;
#pragma unroll
  for (int j = 0; j < 4; j++)
    tile[ty + 8 * j][tx] = recv[(size_t)(b0 + ty + 8 * j) * N_ + (n0 + tx)];
  __syncthreads();
#pragma unroll
  for (int j = 0; j < 4; j++)
    llr_t[(size_t)(n0 + ty + 8 * j) * B_ + (b0 + tx)] =
        2.0f * tile[tx][ty + 8 * j];
}

// Check-node update: one block per check, 256 threads x float4 covers B=1024.
// v2c_i = tot[var(e_i)] - c2v[e_i]  (c2v treated as 0 on the first iteration)
// t_i = tanh(v2c_i/2); loo_i = prod_{j!=i} t_j (prefix/suffix, NO division);
// c2v_new[e_i] = 2*atanh(clip(loo_i))
__global__ __launch_bounds__(256) void check_kernel(
    const int* __restrict__ check_edges, const int* __restrict__ edge_var,
    const float* __restrict__ tot, float* __restrict__ c2v, int first) {
  int r = blockIdx.x;
  int b = threadIdx.x * 4;
  int e[DC_], v[DC_];
#pragma unroll
  for (int i = 0; i < DC_; i++) {
    e[i] = check_edges[r * DC_ + i];
    v[i] = edge_var[e[i]];
  }
  float4 t[DC_];
#pragma unroll
  for (int i = 0; i < DC_; i++) {
    float4 m = *(const float4*)(tot + (size_t)v[i] * B_ + b);
    if (!first) {
      const float4 cv = *(const float4*)(c2v + (size_t)e[i] * B_ + b);
      m.x -= cv.x; m.y -= cv.y; m.z -= cv.z; m.w -= cv.w;
    }
    t[i].x = tanhf(0.5f * m.x);
    t[i].y = tanhf(0.5f * m.y);
    t[i].z = tanhf(0.5f * m.z);
    t[i].w = tanhf(0.5f * m.w);
  }
  // leave-one-out products via prefix/suffix (division-free)
  float4 loo[DC_];
  float4 run = make_float4(1.f, 1.f, 1.f, 1.f);
#pragma unroll
  for (int i = 0; i < DC_; i++) {
    loo[i] = run;
    run.x *= t[i].x; run.y *= t[i].y; run.z *= t[i].z; run.w *= t[i].w;
  }
  run = make_float4(1.f, 1.f, 1.f, 1.f);
#pragma unroll
  for (int i = DC_ - 1; i >= 0; i--) {
    loo[i].x *= run.x; loo[i].y *= run.y; loo[i].z *= run.z; loo[i].w *= run.w;
    run.x *= t[i].x; run.y *= t[i].y; run.z *= t[i].z; run.w *= t[i].w;
  }
#pragma unroll
  for (int i = 0; i < DC_; i++) {
    float4 o;
    o.x = 2.0f * atanhf(clip999(loo[i].x));
    o.y = 2.0f * atanhf(clip999(loo[i].y));
    o.z = 2.0f * atanhf(clip999(loo[i].z));
    o.w = 2.0f * atanhf(clip999(loo[i].w));
    *(float4*)(c2v + (size_t)e[i] * B_ + b) = o;
  }
}

// Variable-node update: tot[v] = llr_t[v] + sum_{j<3} c2v[3v+j].
__global__ __launch_bounds__(256) void var_kernel(
    const float* __restrict__ c2v, const float* __restrict__ llr_t,
    float* __restrict__ tot) {
  int v = blockIdx.x;
  int b = threadIdx.x * 4;
  float4 a0 = *(const float4*)(c2v + (size_t)(3 * v + 0) * B_ + b);
  float4 a1 = *(const float4*)(c2v + (size_t)(3 * v + 1) * B_ + b);
  float4 a2 = *(const float4*)(c2v + (size_t)(3 * v + 2) * B_ + b);
  float4 l = *(const float4*)(llr_t + (size_t)v * B_ + b);
  float4 s;
  s.x = l.x + ((a0.x + a1.x) + a2.x);
  s.y = l.y + ((a0.y + a1.y) + a2.y);
  s.z = l.z + ((a0.z + a1.z) + a2.z);
  s.w = l.w + ((a0.w + a1.w) + a2.w);
  *(float4*)(tot + (size_t)v * B_ + b) = s;
}

// Final: out[0 .. B*N) = final_llrs[b][n] = tot[n][b] (transpose),
//        out[B*N .. 2*B*N) = decoded bits as float (llr < 0 ? 1 : 0).
__global__ __launch_bounds__(256) void final_kernel(
    const float* __restrict__ tot, float* __restrict__ out) {
  __shared__ float tile[32][33];
  int n0 = blockIdx.x * 32;
  int b0 = blockIdx.y * 32;
  int tx = threadIdx.x, ty = threadIdx.y;
#pragma unroll
  for (int j = 0; j < 4; j++)
    tile[ty + 8 * j][tx] = tot[(size_t)(n0 + ty + 8 * j) * B_ + (b0 + tx)];
  __syncthreads();
  const size_t BN = (size_t)B_ * N_;
#pragma unroll
  for (int j = 0; j < 4; j++) {
    float val = tile[tx][ty + 8 * j];
    size_t idx = (size_t)(b0 + ty + 8 * j) * N_ + (n0 + tx);
    out[idx] = val;
    out[BN + idx] = (val < 0.0f) ? 1.0f : 0.0f;
  }
}

extern "C" void kernel_launch(void* const* d_in, const int* in_sizes, int n_in,
                              void* d_out, int out_size, void* d_ws,
                              size_t ws_size, hipStream_t stream) {
  const float* recv = (const float*)d_in[0];     // [B, N]
  const int* edge_var = (const int*)d_in[1];     // [E]
  const int* edge_check = (const int*)d_in[2];   // [E]
  float* out = (float*)d_out;

  char* ws = (char*)d_ws;
  size_t off = 0;
  int* counters = (int*)(ws + off);    off += (size_t)R_ * sizeof(int);        // 16 KB
  int* check_edges = (int*)(ws + off); off += (size_t)R_ * DC_ * sizeof(int);  // 96 KB
  off = (off + 1023) & ~(size_t)1023;
  float* llr_t = (float*)(ws + off);   off += (size_t)N_ * B_ * sizeof(float); // 32 MB
  float* tot = (float*)(ws + off);     off += (size_t)N_ * B_ * sizeof(float); // 32 MB
  float* c2v = (float*)(ws + off);     off += (size_t)E_ * B_ * sizeof(float); // 96 MB

  hipMemsetAsync(counters, 0, (size_t)R_ * sizeof(int), stream);
  build_edges_kernel<<<(E_ + 255) / 256, 256, 0, stream>>>(edge_check, counters,
                                                           check_edges);
  sort_edges_kernel<<<(R_ + 255) / 256, 256, 0, stream>>>(check_edges);
  transpose_llr_kernel<<<dim3(N_ / 32, B_ / 32), dim3(32, 8), 0, stream>>>(
      recv, llr_t);

  for (int it = 0; it < ITERS_; it++) {
    check_kernel<<<R_, 256, 0, stream>>>(check_edges, edge_var,
                                         (it == 0) ? llr_t : tot, c2v,
                                         (it == 0) ? 1 : 0);
    var_kernel<<<N_, 256, 0, stream>>>(c2v, llr_t, tot);
  }

  final_kernel<<<dim3(N_ / 32, B_ / 32), dim3(32, 8), 0, stream>>>(tot, out);
}

// Round 4
// 805.221 us; speedup vs baseline: 1.5593x; 1.5593x over previous
//
#include <hip/hip_runtime.h>

// LDPC sum-product BP decode, (3,6)-regular, N=8192, R=4096, B=1024, 10 iters.
// State kept across half-iterations: c2v [E,B] and tot [N,B] (v2c = tot[var]-c2v).
// All big arrays are B-contiguous so each node/edge row is a coalesced 4KB read.
//
// R3: check_kernel was VALU-bound (VALUBusy 91%, HBM 26%) on library
// tanhf/atanhf. Replaced with hw-pipe math: v_exp_f32/v_log_f32/v_rcp_f32.
//   tanh(m/2) = (e^|m|-1)/(e^|m|+1), sign restored; |m| capped at 20
//   2*atanh(y) = ln2 * log2((1+y)/(1-y))
// Division-free prefix/suffix LOO products (R2) retained: no 0/0 NaN path.

#define N_  8192
#define R_  4096
#define DV_ 3
#define DC_ 6
#define E_  (N_ * DV_)
#define B_  1024
#define ITERS_ 10

__device__ __forceinline__ float clip999(float x) {
  if (x > 0.999f) return 0.999f;
  if (x < -0.999f) return -0.999f;
  return x;
}

// tanh(m/2) via e^|m| on the hw exp pipe. Cap avoids exp overflow (inf/inf);
// tanh(m/2) rounds to 1.0f for |m| >~ 18 anyway.
__device__ __forceinline__ float fast_tanh_half(float m) {
  float a = fminf(fabsf(m), 20.0f);
  float E = __builtin_amdgcn_exp2f(a * 1.44269504f);  // e^a
  float t = (E - 1.0f) * __builtin_amdgcn_rcpf(E + 1.0f);
  return copysignf(t, m);
}

// 2*atanh(y) = ln((1+y)/(1-y)); y in [-0.999, 0.999] so q in [5e-4, 1999].
__device__ __forceinline__ float fast_2atanh(float y) {
  float q = (1.0f + y) * __builtin_amdgcn_rcpf(1.0f - y);
  return 0.69314718f * __builtin_amdgcn_logf(q);  // v_log_f32 = log2
}

// Pass 1: scatter edges into per-check rows (slot order nondeterministic).
__global__ __launch_bounds__(256) void build_edges_kernel(
    const int* __restrict__ edge_check, int* __restrict__ counters,
    int* __restrict__ check_edges) {
  int e = blockIdx.x * 256 + threadIdx.x;
  if (e < E_) {
    int r = edge_check[e];
    int s = atomicAdd(&counters[r], 1);
    check_edges[r * DC_ + s] = e;
  }
}

// Pass 2: sort each 6-entry row ascending (optimal 12-comparator network).
// Makes the table deterministic regardless of atomic scheduling.
__global__ __launch_bounds__(256) void sort_edges_kernel(
    int* __restrict__ check_edges) {
  int r = blockIdx.x * 256 + threadIdx.x;
  if (r >= R_) return;
  int e0 = check_edges[r * DC_ + 0], e1 = check_edges[r * DC_ + 1];
  int e2 = check_edges[r * DC_ + 2], e3 = check_edges[r * DC_ + 3];
  int e4 = check_edges[r * DC_ + 4], e5 = check_edges[r * DC_ + 5];
#define CSWAP(a, b) { int lo = min(a, b), hi = max(a, b); a = lo; b = hi; }
  CSWAP(e0, e5) CSWAP(e1, e3) CSWAP(e2, e4)
  CSWAP(e1, e2) CSWAP(e3, e4)
  CSWAP(e0, e3) CSWAP(e2, e5)
  CSWAP(e0, e1) CSWAP(e2, e3) CSWAP(e4, e5)
  CSWAP(e1, e2) CSWAP(e3, e4)
#undef CSWAP
  check_edges[r * DC_ + 0] = e0; check_edges[r * DC_ + 1] = e1;
  check_edges[r * DC_ + 2] = e2; check_edges[r * DC_ + 3] = e3;
  check_edges[r * DC_ + 4] = e4; check_edges[r * DC_ + 5] = e5;
}

// llr_t[n][b] = 2 * received[b][n]   (tiled transpose, 32x32)
__global__ __launch_bounds__(256) void transpose_llr_kernel(
    const float* __restrict__ recv, float* __restrict__ llr_t) {
  __shared__ float tile[32][33];
  int n0 = blockIdx.x * 32;
  int b0 = blockIdx.y * 32;
  int tx = threadIdx.x, ty = threadIdx.y;
#pragma unroll
  for (int j = 0; j < 4; j++)
    tile[ty + 8 * j][tx] = recv[(size_t)(b0 + ty + 8 * j) * N_ + (n0 + tx)];
  __syncthreads();
#pragma unroll
  for (int j = 0; j < 4; j++)
    llr_t[(size_t)(n0 + ty + 8 * j) * B_ + (b0 + tx)] =
        2.0f * tile[tx][ty + 8 * j];
}

// Check-node update: one block per check, 256 threads x float4 covers B=1024.
// v2c_i = tot[var(e_i)] - c2v[e_i]  (c2v treated as 0 on the first iteration)
// t_i = tanh(v2c_i/2); loo_i = prod_{j!=i} t_j (prefix/suffix, NO division);
// c2v_new[e_i] = 2*atanh(clip(loo_i))
__global__ __launch_bounds__(256) void check_kernel(
    const int* __restrict__ check_edges, const int* __restrict__ edge_var,
    const float* __restrict__ tot, float* __restrict__ c2v, int first) {
  int r = blockIdx.x;
  int b = threadIdx.x * 4;
  int e[DC_], v[DC_];
#pragma unroll
  for (int i = 0; i < DC_; i++) {
    e[i] = check_edges[r * DC_ + i];
    v[i] = edge_var[e[i]];
  }
  float4 t[DC_];
#pragma unroll
  for (int i = 0; i < DC_; i++) {
    float4 m = *(const float4*)(tot + (size_t)v[i] * B_ + b);
    if (!first) {
      const float4 cv = *(const float4*)(c2v + (size_t)e[i] * B_ + b);
      m.x -= cv.x; m.y -= cv.y; m.z -= cv.z; m.w -= cv.w;
    }
    t[i].x = fast_tanh_half(m.x);
    t[i].y = fast_tanh_half(m.y);
    t[i].z = fast_tanh_half(m.z);
    t[i].w = fast_tanh_half(m.w);
  }
  // leave-one-out products via prefix/suffix (division-free)
  float4 loo[DC_];
  float4 run = make_float4(1.f, 1.f, 1.f, 1.f);
#pragma unroll
  for (int i = 0; i < DC_; i++) {
    loo[i] = run;
    run.x *= t[i].x; run.y *= t[i].y; run.z *= t[i].z; run.w *= t[i].w;
  }
  run = make_float4(1.f, 1.f, 1.f, 1.f);
#pragma unroll
  for (int i = DC_ - 1; i >= 0; i--) {
    loo[i].x *= run.x; loo[i].y *= run.y; loo[i].z *= run.z; loo[i].w *= run.w;
    run.x *= t[i].x; run.y *= t[i].y; run.z *= t[i].z; run.w *= t[i].w;
  }
#pragma unroll
  for (int i = 0; i < DC_; i++) {
    float4 o;
    o.x = fast_2atanh(clip999(loo[i].x));
    o.y = fast_2atanh(clip999(loo[i].y));
    o.z = fast_2atanh(clip999(loo[i].z));
    o.w = fast_2atanh(clip999(loo[i].w));
    *(float4*)(c2v + (size_t)e[i] * B_ + b) = o;
  }
}

// Variable-node update: tot[v] = llr_t[v] + sum_{j<3} c2v[3v+j].
__global__ __launch_bounds__(256) void var_kernel(
    const float* __restrict__ c2v, const float* __restrict__ llr_t,
    float* __restrict__ tot) {
  int v = blockIdx.x;
  int b = threadIdx.x * 4;
  float4 a0 = *(const float4*)(c2v + (size_t)(3 * v + 0) * B_ + b);
  float4 a1 = *(const float4*)(c2v + (size_t)(3 * v + 1) * B_ + b);
  float4 a2 = *(const float4*)(c2v + (size_t)(3 * v + 2) * B_ + b);
  float4 l = *(const float4*)(llr_t + (size_t)v * B_ + b);
  float4 s;
  s.x = l.x + ((a0.x + a1.x) + a2.x);
  s.y = l.y + ((a0.y + a1.y) + a2.y);
  s.z = l.z + ((a0.z + a1.z) + a2.z);
  s.w = l.w + ((a0.w + a1.w) + a2.w);
  *(float4*)(tot + (size_t)v * B_ + b) = s;
}

// Final: out[0 .. B*N) = final_llrs[b][n] = tot[n][b] (transpose),
//        out[B*N .. 2*B*N) = decoded bits as float (llr < 0 ? 1 : 0).
__global__ __launch_bounds__(256) void final_kernel(
    const float* __restrict__ tot, float* __restrict__ out) {
  __shared__ float tile[32][33];
  int n0 = blockIdx.x * 32;
  int b0 = blockIdx.y * 32;
  int tx = threadIdx.x, ty = threadIdx.y;
#pragma unroll
  for (int j = 0; j < 4; j++)
    tile[ty + 8 * j][tx] = tot[(size_t)(n0 + ty + 8 * j) * B_ + (b0 + tx)];
  __syncthreads();
  const size_t BN = (size_t)B_ * N_;
#pragma unroll
  for (int j = 0; j < 4; j++) {
    float val = tile[tx][ty + 8 * j];
    size_t idx = (size_t)(b0 + ty + 8 * j) * N_ + (n0 + tx);
    out[idx] = val;
    out[BN + idx] = (val < 0.0f) ? 1.0f : 0.0f;
  }
}

extern "C" void kernel_launch(void* const* d_in, const int* in_sizes, int n_in,
                              void* d_out, int out_size, void* d_ws,
                              size_t ws_size, hipStream_t stream) {
  const float* recv = (const float*)d_in[0];     // [B, N]
  const int* edge_var = (const int*)d_in[1];     // [E]
  const int* edge_check = (const int*)d_in[2];   // [E]
  float* out = (float*)d_out;

  char* ws = (char*)d_ws;
  size_t off = 0;
  int* counters = (int*)(ws + off);    off += (size_t)R_ * sizeof(int);        // 16 KB
  int* check_edges = (int*)(ws + off); off += (size_t)R_ * DC_ * sizeof(int);  // 96 KB
  off = (off + 1023) & ~(size_t)1023;
  float* llr_t = (float*)(ws + off);   off += (size_t)N_ * B_ * sizeof(float); // 32 MB
  float* tot = (float*)(ws + off);     off += (size_t)N_ * B_ * sizeof(float); // 32 MB
  float* c2v = (float*)(ws + off);     off += (size_t)E_ * B_ * sizeof(float); // 96 MB

  hipMemsetAsync(counters, 0, (size_t)R_ * sizeof(int), stream);
  build_edges_kernel<<<(E_ + 255) / 256, 256, 0, stream>>>(edge_check, counters,
                                                           check_edges);
  sort_edges_kernel<<<(R_ + 255) / 256, 256, 0, stream>>>(check_edges);
  transpose_llr_kernel<<<dim3(N_ / 32, B_ / 32), dim3(32, 8), 0, stream>>>(
      recv, llr_t);

  for (int it = 0; it < ITERS_; it++) {
    check_kernel<<<R_, 256, 0, stream>>>(check_edges, edge_var,
                                         (it == 0) ? llr_t : tot, c2v,
                                         (it == 0) ? 1 : 0);
    var_kernel<<<N_, 256, 0, stream>>>(c2v, llr_t, tot);
  }

  final_kernel<<<dim3(N_ / 32, B_ / 32), dim3(32, 8), 0, stream>>>(tot, out);
}

// Round 6
// 352.927 us; speedup vs baseline: 3.5576x; 2.2816x over previous
//
#include <hip/hip_runtime.h>

// LDPC sum-product BP decode, (3,6)-regular, N=8192, R=4096, B=1024, 10 iters.
//
// R5: PERSISTENT-LDS design. One workgroup per batch element; all BP state
// (c2v[E]=96KB f32 + tot[N]=32KB f32 = 128KB) lives in LDS for all 10
// iterations. HBM traffic ~100MB total (recv in, out out) vs ~3GB for the
// kernel-per-phase design. f32 everywhere: R5's fp16 c2v flipped a decoded
// bit (hard-threshold output!) — f32 numerics are the proven-safe point.
// Arithmetic is op-identical to the passing R4 bench (absmax 0.03125).
//
// R3: hw-pipe transcendentals (v_exp/v_log/v_rcp).
// R2: division-free prefix/suffix LOO products -> no 0/0 NaN path;
//     deterministic edge table (atomic build + per-row sorting network).

#define N_  8192
#define R_  4096
#define DV_ 3
#define DC_ 6
#define E_  (N_ * DV_)
#define B_  1024
#define ITERS_ 10

#define THREADS_ 512
#define CPT_ (R_ / THREADS_)  // 8 checks per thread

__device__ __forceinline__ float clip999(float x) {
  if (x > 0.999f) return 0.999f;
  if (x < -0.999f) return -0.999f;
  return x;
}

// tanh(m/2) via e^|m| on the hw exp pipe. Cap avoids exp overflow (inf/inf);
// tanh(m/2) rounds to 1.0f for |m| >~ 18 anyway.
__device__ __forceinline__ float fast_tanh_half(float m) {
  float a = fminf(fabsf(m), 20.0f);
  float E = __builtin_amdgcn_exp2f(a * 1.44269504f);  // e^a
  float t = (E - 1.0f) * __builtin_amdgcn_rcpf(E + 1.0f);
  return copysignf(t, m);
}

// 2*atanh(y) = ln((1+y)/(1-y)); y in [-0.999, 0.999] so q in [5e-4, 1999].
__device__ __forceinline__ float fast_2atanh(float y) {
  float q = (1.0f + y) * __builtin_amdgcn_rcpf(1.0f - y);
  return 0.69314718f * __builtin_amdgcn_logf(q);  // v_log_f32 = log2
}

// Pass 1: scatter edges into per-check rows (slot order nondeterministic).
__global__ __launch_bounds__(256) void build_edges_kernel(
    const int* __restrict__ edge_check, int* __restrict__ counters,
    int* __restrict__ check_edges) {
  int e = blockIdx.x * 256 + threadIdx.x;
  if (e < E_) {
    int r = edge_check[e];
    int s = atomicAdd(&counters[r], 1);
    check_edges[r * DC_ + s] = e;
  }
}

// Pass 2: sort each 6-entry row ascending (optimal 12-comparator network).
// Makes the table deterministic regardless of atomic scheduling.
__global__ __launch_bounds__(256) void sort_edges_kernel(
    int* __restrict__ check_edges) {
  int r = blockIdx.x * 256 + threadIdx.x;
  if (r >= R_) return;
  int e0 = check_edges[r * DC_ + 0], e1 = check_edges[r * DC_ + 1];
  int e2 = check_edges[r * DC_ + 2], e3 = check_edges[r * DC_ + 3];
  int e4 = check_edges[r * DC_ + 4], e5 = check_edges[r * DC_ + 5];
#define CSWAP(a, b) { int lo = min(a, b), hi = max(a, b); a = lo; b = hi; }
  CSWAP(e0, e5) CSWAP(e1, e3) CSWAP(e2, e4)
  CSWAP(e1, e2) CSWAP(e3, e4)
  CSWAP(e0, e3) CSWAP(e2, e5)
  CSWAP(e0, e1) CSWAP(e2, e3) CSWAP(e4, e5)
  CSWAP(e1, e2) CSWAP(e3, e4)
#undef CSWAP
  check_edges[r * DC_ + 0] = e0; check_edges[r * DC_ + 1] = e1;
  check_edges[r * DC_ + 2] = e2; check_edges[r * DC_ + 3] = e3;
  check_edges[r * DC_ + 4] = e4; check_edges[r * DC_ + 5] = e5;
}

// Persistent BP: block b decodes batch element b entirely in LDS.
// tot[v] = llr[v] + sum c2v ; v2c = tot[var(e)] - c2v[e] (c2v starts 0).
__global__ __launch_bounds__(THREADS_, 1) void persistent_kernel(
    const float* __restrict__ recv, const int* __restrict__ check_edges,
    float* __restrict__ out) {
  __shared__ float c2v_s[E_];  // 96 KB
  __shared__ float tot_s[N_];  // 32 KB
  const int b = blockIdx.x;
  const int tid = threadIdx.x;
  const float* r = recv + (size_t)b * N_;

  // This thread's 8 check rows -> registers, reused for all 10 iterations.
  int eidx[CPT_][DC_];
#pragma unroll
  for (int c = 0; c < CPT_; c++) {
    int rr = c * THREADS_ + tid;
#pragma unroll
    for (int i = 0; i < DC_; i++) eidx[c][i] = check_edges[rr * DC_ + i];
  }

  // init: tot = llr = 2*recv_row, c2v = 0
  for (int n = tid; n < N_; n += THREADS_) tot_s[n] = 2.0f * r[n];
  for (int e = tid; e < E_; e += THREADS_) c2v_s[e] = 0.0f;
  __syncthreads();

  for (int iter = 0; iter < ITERS_; iter++) {
    // ---- check phase ----
#pragma unroll
    for (int c = 0; c < CPT_; c++) {
      float t[DC_];
#pragma unroll
      for (int i = 0; i < DC_; i++) {
        int e = eidx[c][i];
        int v = (int)((unsigned)e / 3u);  // edge_var[e] == e/3 by construction
        float m = tot_s[v] - c2v_s[e];
        t[i] = fast_tanh_half(m);
      }
      float loo[DC_];
      float run = 1.0f;
#pragma unroll
      for (int i = 0; i < DC_; i++) { loo[i] = run; run *= t[i]; }
      run = 1.0f;
#pragma unroll
      for (int i = DC_ - 1; i >= 0; i--) { loo[i] *= run; run *= t[i]; }
#pragma unroll
      for (int i = 0; i < DC_; i++)
        c2v_s[eidx[c][i]] = fast_2atanh(clip999(loo[i]));
    }
    __syncthreads();
    // ---- variable phase ----
    for (int v = tid; v < N_; v += THREADS_) {
      float llr = 2.0f * r[v];  // L1-resident re-read (contiguous 32KB row)
      tot_s[v] =
          llr + ((c2v_s[3 * v] + c2v_s[3 * v + 1]) + c2v_s[3 * v + 2]);
    }
    __syncthreads();
  }

  // ---- output: LLRs then hard bits, directly in [B,N] layout ----
  const size_t BN = (size_t)B_ * N_;
  for (int n = tid; n < N_; n += THREADS_) {
    float val = tot_s[n];
    out[(size_t)b * N_ + n] = val;
    out[BN + (size_t)b * N_ + n] = (val < 0.0f) ? 1.0f : 0.0f;
  }
}

extern "C" void kernel_launch(void* const* d_in, const int* in_sizes, int n_in,
                              void* d_out, int out_size, void* d_ws,
                              size_t ws_size, hipStream_t stream) {
  const float* recv = (const float*)d_in[0];     // [B, N]
  const int* edge_check = (const int*)d_in[2];   // [E]
  float* out = (float*)d_out;

  char* ws = (char*)d_ws;
  size_t off = 0;
  int* counters = (int*)(ws + off);    off += (size_t)R_ * sizeof(int);        // 16 KB
  int* check_edges = (int*)(ws + off); off += (size_t)R_ * DC_ * sizeof(int);  // 96 KB

  hipMemsetAsync(counters, 0, (size_t)R_ * sizeof(int), stream);
  build_edges_kernel<<<(E_ + 255) / 256, 256, 0, stream>>>(edge_check, counters,
                                                           check_edges);
  sort_edges_kernel<<<(R_ + 255) / 256, 256, 0, stream>>>(check_edges);
  persistent_kernel<<<B_, THREADS_, 0, stream>>>(recv, check_edges, out);
}

// Round 7
// 292.323 us; speedup vs baseline: 4.2952x; 1.2073x over previous
//
#include <hip/hip_runtime.h>

// LDPC sum-product BP decode, (3,6)-regular, N=8192, R=4096, B=1024, 10 iters.
//
// R6: persistent-LDS design — one workgroup per batch element, all state in
// LDS (c2v[E] 96KB + tot[N] 32KB), HBM ~84MB/launch. f32 everywhere (fp16
// c2v flipped a hard-decision bit in R5 — f32 is the proven-safe point).
//
// R7: (a) THREADS 512->1024: 2->4 waves/SIMD to hide trans+LDS latency
//     (R6: VALUBusy 62%, Occupancy 23%).
//     (b) previous c2v kept in REGISTERS (each thread owns its 4 checks for
//     all 10 iters) — kills the 6 random c2v LDS reads per check; random
//     LDS lane-ops drop 18->12 per check (R6: 5.9e7 conflict cycles).
//     Arithmetic order unchanged -> bit-identical to R6's passing result.
//
// R3: hw-pipe transcendentals (v_exp/v_log/v_rcp).
// R2: division-free prefix/suffix LOO products -> no 0/0 NaN path;
//     deterministic edge table (atomic build + per-row sorting network).

#define N_  8192
#define R_  4096
#define DV_ 3
#define DC_ 6
#define E_  (N_ * DV_)
#define B_  1024
#define ITERS_ 10

#define THREADS_ 1024
#define CPT_ (R_ / THREADS_)  // 4 checks per thread

__device__ __forceinline__ float clip999(float x) {
  if (x > 0.999f) return 0.999f;
  if (x < -0.999f) return -0.999f;
  return x;
}

// tanh(m/2) via e^|m| on the hw exp pipe. Cap avoids exp overflow (inf/inf);
// tanh(m/2) rounds to 1.0f for |m| >~ 18 anyway.
__device__ __forceinline__ float fast_tanh_half(float m) {
  float a = fminf(fabsf(m), 20.0f);
  float E = __builtin_amdgcn_exp2f(a * 1.44269504f);  // e^a
  float t = (E - 1.0f) * __builtin_amdgcn_rcpf(E + 1.0f);
  return copysignf(t, m);
}

// 2*atanh(y) = ln((1+y)/(1-y)); y in [-0.999, 0.999] so q in [5e-4, 1999].
__device__ __forceinline__ float fast_2atanh(float y) {
  float q = (1.0f + y) * __builtin_amdgcn_rcpf(1.0f - y);
  return 0.69314718f * __builtin_amdgcn_logf(q);  // v_log_f32 = log2
}

// Pass 1: scatter edges into per-check rows (slot order nondeterministic).
__global__ __launch_bounds__(256) void build_edges_kernel(
    const int* __restrict__ edge_check, int* __restrict__ counters,
    int* __restrict__ check_edges) {
  int e = blockIdx.x * 256 + threadIdx.x;
  if (e < E_) {
    int r = edge_check[e];
    int s = atomicAdd(&counters[r], 1);
    check_edges[r * DC_ + s] = e;
  }
}

// Pass 2: sort each 6-entry row ascending (optimal 12-comparator network).
// Makes the table deterministic regardless of atomic scheduling.
__global__ __launch_bounds__(256) void sort_edges_kernel(
    int* __restrict__ check_edges) {
  int r = blockIdx.x * 256 + threadIdx.x;
  if (r >= R_) return;
  int e0 = check_edges[r * DC_ + 0], e1 = check_edges[r * DC_ + 1];
  int e2 = check_edges[r * DC_ + 2], e3 = check_edges[r * DC_ + 3];
  int e4 = check_edges[r * DC_ + 4], e5 = check_edges[r * DC_ + 5];
#define CSWAP(a, b) { int lo = min(a, b), hi = max(a, b); a = lo; b = hi; }
  CSWAP(e0, e5) CSWAP(e1, e3) CSWAP(e2, e4)
  CSWAP(e1, e2) CSWAP(e3, e4)
  CSWAP(e0, e3) CSWAP(e2, e5)
  CSWAP(e0, e1) CSWAP(e2, e3) CSWAP(e4, e5)
  CSWAP(e1, e2) CSWAP(e3, e4)
#undef CSWAP
  check_edges[r * DC_ + 0] = e0; check_edges[r * DC_ + 1] = e1;
  check_edges[r * DC_ + 2] = e2; check_edges[r * DC_ + 3] = e3;
  check_edges[r * DC_ + 4] = e4; check_edges[r * DC_ + 5] = e5;
}

// Persistent BP: block b decodes batch element b entirely in LDS.
// tot[v] = llr[v] + sum c2v ; v2c = tot[var(e)] - c2v[e] (c2v starts 0).
__global__ __launch_bounds__(THREADS_) void persistent_kernel(
    const float* __restrict__ recv, const int* __restrict__ check_edges,
    float* __restrict__ out) {
  __shared__ float c2v_s[E_];  // 96 KB (var-major: e = 3v+j)
  __shared__ float tot_s[N_];  // 32 KB
  const int b = blockIdx.x;
  const int tid = threadIdx.x;
  const float* r = recv + (size_t)b * N_;

  // This thread's 4 check rows -> registers, reused for all 10 iterations.
  int eidx[CPT_][DC_];
#pragma unroll
  for (int c = 0; c < CPT_; c++) {
    int rr = c * THREADS_ + tid;
#pragma unroll
    for (int i = 0; i < DC_; i++) eidx[c][i] = check_edges[rr * DC_ + i];
  }
  // Previous c2v for the owned checks lives in registers (starts at 0).
  float c2v_reg[CPT_][DC_];
#pragma unroll
  for (int c = 0; c < CPT_; c++)
#pragma unroll
    for (int i = 0; i < DC_; i++) c2v_reg[c][i] = 0.0f;

  // init: tot = llr = 2*recv_row
  for (int n = tid; n < N_; n += THREADS_) tot_s[n] = 2.0f * r[n];
  __syncthreads();

  for (int iter = 0; iter < ITERS_; iter++) {
    // ---- check phase: random tot reads + random c2v writes; prev c2v in
    // registers (no LDS read) ----
#pragma unroll
    for (int c = 0; c < CPT_; c++) {
      float t[DC_];
#pragma unroll
      for (int i = 0; i < DC_; i++) {
        int e = eidx[c][i];
        int v = (int)((unsigned)e / 3u);  // edge_var[e] == e/3 by construction
        float m = tot_s[v] - c2v_reg[c][i];
        t[i] = fast_tanh_half(m);
      }
      float loo[DC_];
      float run = 1.0f;
#pragma unroll
      for (int i = 0; i < DC_; i++) { loo[i] = run; run *= t[i]; }
      run = 1.0f;
#pragma unroll
      for (int i = DC_ - 1; i >= 0; i--) { loo[i] *= run; run *= t[i]; }
#pragma unroll
      for (int i = 0; i < DC_; i++) {
        float nc = fast_2atanh(clip999(loo[i]));
        c2v_reg[c][i] = nc;
        c2v_s[eidx[c][i]] = nc;
      }
    }
    __syncthreads();
    // ---- variable phase (contiguous stride-3 reads: 2-way aliasing, free) ----
    for (int v = tid; v < N_; v += THREADS_) {
      float llr = 2.0f * r[v];  // L1-resident re-read (contiguous 32KB row)
      tot_s[v] =
          llr + ((c2v_s[3 * v] + c2v_s[3 * v + 1]) + c2v_s[3 * v + 2]);
    }
    __syncthreads();
  }

  // ---- output: LLRs then hard bits, directly in [B,N] layout ----
  const size_t BN = (size_t)B_ * N_;
  for (int n = tid; n < N_; n += THREADS_) {
    float val = tot_s[n];
    out[(size_t)b * N_ + n] = val;
    out[BN + (size_t)b * N_ + n] = (val < 0.0f) ? 1.0f : 0.0f;
  }
}

extern "C" void kernel_launch(void* const* d_in, const int* in_sizes, int n_in,
                              void* d_out, int out_size, void* d_ws,
                              size_t ws_size, hipStream_t stream) {
  const float* recv = (const float*)d_in[0];     // [B, N]
  const int* edge_check = (const int*)d_in[2];   // [E]
  float* out = (float*)d_out;

  char* ws = (char*)d_ws;
  size_t off = 0;
  int* counters = (int*)(ws + off);    off += (size_t)R_ * sizeof(int);        // 16 KB
  int* check_edges = (int*)(ws + off); off += (size_t)R_ * DC_ * sizeof(int);  // 96 KB

  hipMemsetAsync(counters, 0, (size_t)R_ * sizeof(int), stream);
  build_edges_kernel<<<(E_ + 255) / 256, 256, 0, stream>>>(edge_check, counters,
                                                           check_edges);
  sort_edges_kernel<<<(R_ + 255) / 256, 256, 0, stream>>>(check_edges);
  persistent_kernel<<<B_, THREADS_, 0, stream>>>(recv, check_edges, out);
}

// Round 9
// 290.959 us; speedup vs baseline: 4.3153x; 1.0047x over previous
//
#include <hip/hip_runtime.h>

// LDPC sum-product BP decode, (3,6)-regular, N=8192, R=4096, B=1024, 10 iters.
//
// R6: persistent-LDS design — one workgroup per batch element, all state in
// LDS (c2v[E] 96KB + tot[N] 32KB), HBM ~84MB/launch. f32 everywhere (fp16
// c2v flipped a hard-decision bit in R5).
// R7: 1024 threads (4 waves/SIMD), prev c2v in registers (thread owns its
// 4 checks all 10 iters) — random LDS lane-ops 18->12 per check.
// R8 POST-MORTEM: n/d-form LOO products suffered catastrophic cancellation
// (Nd-Nn of two ~1e36 products) -> NaN -> wrong-sign clamp -> bit flip.
// REVERTED to R7's proven tanh/atanh path (absmax 0.03125, passed).
// R9 (this round, arithmetic-identical to R7):
//   - v = e/3 precomputed into registers (kills ~100 VALU ops/thread/iter
//     of magic-division address math in the hot loop)
//   - channel LLRs preloaded to registers (kills 80 global re-reads/thread)
//
// R3: hw-pipe transcendentals (v_exp/v_log/v_rcp).
// R2: division-free prefix/suffix LOO products -> no 0/0 NaN path;
//     deterministic edge table (atomic build + per-row sorting network).

#define N_  8192
#define R_  4096
#define DV_ 3
#define DC_ 6
#define E_  (N_ * DV_)
#define B_  1024
#define ITERS_ 10

#define THREADS_ 1024
#define CPT_ (R_ / THREADS_)   // 4 checks per thread
#define VPT_ (N_ / THREADS_)   // 8 variables per thread

__device__ __forceinline__ float clip999(float x) {
  if (x > 0.999f) return 0.999f;
  if (x < -0.999f) return -0.999f;
  return x;
}

// tanh(m/2) via e^|m| on the hw exp pipe. Cap avoids exp overflow (inf/inf);
// tanh(m/2) rounds to 1.0f for |m| >~ 18 anyway.
__device__ __forceinline__ float fast_tanh_half(float m) {
  float a = fminf(fabsf(m), 20.0f);
  float E = __builtin_amdgcn_exp2f(a * 1.44269504f);  // e^a
  float t = (E - 1.0f) * __builtin_amdgcn_rcpf(E + 1.0f);
  return copysignf(t, m);
}

// 2*atanh(y) = ln((1+y)/(1-y)); y in [-0.999, 0.999] so q in [5e-4, 1999].
__device__ __forceinline__ float fast_2atanh(float y) {
  float q = (1.0f + y) * __builtin_amdgcn_rcpf(1.0f - y);
  return 0.69314718f * __builtin_amdgcn_logf(q);  // v_log_f32 = log2
}

// Pass 1: scatter edges into per-check rows (slot order nondeterministic).
__global__ __launch_bounds__(256) void build_edges_kernel(
    const int* __restrict__ edge_check, int* __restrict__ counters,
    int* __restrict__ check_edges) {
  int e = blockIdx.x * 256 + threadIdx.x;
  if (e < E_) {
    int r = edge_check[e];
    int s = atomicAdd(&counters[r], 1);
    check_edges[r * DC_ + s] = e;
  }
}

// Pass 2: sort each 6-entry row ascending (optimal 12-comparator network).
// Makes the table deterministic regardless of atomic scheduling.
__global__ __launch_bounds__(256) void sort_edges_kernel(
    int* __restrict__ check_edges) {
  int r = blockIdx.x * 256 + threadIdx.x;
  if (r >= R_) return;
  int e0 = check_edges[r * DC_ + 0], e1 = check_edges[r * DC_ + 1];
  int e2 = check_edges[r * DC_ + 2], e3 = check_edges[r * DC_ + 3];
  int e4 = check_edges[r * DC_ + 4], e5 = check_edges[r * DC_ + 5];
#define CSWAP(a, b) { int lo = min(a, b), hi = max(a, b); a = lo; b = hi; }
  CSWAP(e0, e5) CSWAP(e1, e3) CSWAP(e2, e4)
  CSWAP(e1, e2) CSWAP(e3, e4)
  CSWAP(e0, e3) CSWAP(e2, e5)
  CSWAP(e0, e1) CSWAP(e2, e3) CSWAP(e4, e5)
  CSWAP(e1, e2) CSWAP(e3, e4)
#undef CSWAP
  check_edges[r * DC_ + 0] = e0; check_edges[r * DC_ + 1] = e1;
  check_edges[r * DC_ + 2] = e2; check_edges[r * DC_ + 3] = e3;
  check_edges[r * DC_ + 4] = e4; check_edges[r * DC_ + 5] = e5;
}

// Persistent BP: block b decodes batch element b entirely in LDS.
// tot[v] = llr[v] + sum c2v ; v2c = tot[var(e)] - c2v[e] (c2v starts 0).
__global__ __launch_bounds__(THREADS_) void persistent_kernel(
    const float* __restrict__ recv, const int* __restrict__ check_edges,
    float* __restrict__ out) {
  __shared__ float c2v_s[E_];  // 96 KB (var-major: e = 3v+j)
  __shared__ float tot_s[N_];  // 32 KB
  const int b = blockIdx.x;
  const int tid = threadIdx.x;
  const float* r = recv + (size_t)b * N_;

  // This thread's 4 check rows -> registers (edge idx AND var idx), reused
  // for all 10 iterations. vidx precompute kills the magic-div in the loop.
  int eidx[CPT_][DC_];
  int vidx[CPT_][DC_];
#pragma unroll
  for (int c = 0; c < CPT_; c++) {
    int rr = c * THREADS_ + tid;
#pragma unroll
    for (int i = 0; i < DC_; i++) {
      int e = check_edges[rr * DC_ + i];
      eidx[c][i] = e;
      vidx[c][i] = (int)((unsigned)e / 3u);  // edge_var[e] == e/3 by construction
    }
  }
  // Previous c2v for the owned checks lives in registers (starts at 0).
  float c2v_reg[CPT_][DC_];
#pragma unroll
  for (int c = 0; c < CPT_; c++)
#pragma unroll
    for (int i = 0; i < DC_; i++) c2v_reg[c][i] = 0.0f;

  // Channel LLRs this thread needs in the var phase -> registers.
  float llr_reg[VPT_];
#pragma unroll
  for (int k = 0; k < VPT_; k++)
    llr_reg[k] = 2.0f * r[tid + k * THREADS_];

  // init: tot = llr
#pragma unroll
  for (int k = 0; k < VPT_; k++) tot_s[tid + k * THREADS_] = llr_reg[k];
  __syncthreads();

  for (int iter = 0; iter < ITERS_; iter++) {
    // ---- check phase: random tot reads + random c2v writes; prev c2v in
    // registers (no LDS read) ----
#pragma unroll
    for (int c = 0; c < CPT_; c++) {
      float t[DC_];
#pragma unroll
      for (int i = 0; i < DC_; i++) {
        float m = tot_s[vidx[c][i]] - c2v_reg[c][i];
        t[i] = fast_tanh_half(m);
      }
      float loo[DC_];
      float run = 1.0f;
#pragma unroll
      for (int i = 0; i < DC_; i++) { loo[i] = run; run *= t[i]; }
      run = 1.0f;
#pragma unroll
      for (int i = DC_ - 1; i >= 0; i--) { loo[i] *= run; run *= t[i]; }
#pragma unroll
      for (int i = 0; i < DC_; i++) {
        float nc = fast_2atanh(clip999(loo[i]));
        c2v_reg[c][i] = nc;
        c2v_s[eidx[c][i]] = nc;
      }
    }
    __syncthreads();
    // ---- variable phase (contiguous stride-3 reads: conflict-benign) ----
#pragma unroll
    for (int k = 0; k < VPT_; k++) {
      int v = tid + k * THREADS_;
      tot_s[v] =
          llr_reg[k] + ((c2v_s[3 * v] + c2v_s[3 * v + 1]) + c2v_s[3 * v + 2]);
    }
    __syncthreads();
  }

  // ---- output: LLRs then hard bits, directly in [B,N] layout ----
  const size_t BN = (size_t)B_ * N_;
#pragma unroll
  for (int k = 0; k < VPT_; k++) {
    int n = tid + k * THREADS_;
    float val = tot_s[n];
    out[(size_t)b * N_ + n] = val;
    out[BN + (size_t)b * N_ + n] = (val < 0.0f) ? 1.0f : 0.0f;
  }
}

extern "C" void kernel_launch(void* const* d_in, const int* in_sizes, int n_in,
                              void* d_out, int out_size, void* d_ws,
                              size_t ws_size, hipStream_t stream) {
  const float* recv = (const float*)d_in[0];     // [B, N]
  const int* edge_check = (const int*)d_in[2];   // [E]
  float* out = (float*)d_out;

  char* ws = (char*)d_ws;
  size_t off = 0;
  int* counters = (int*)(ws + off);    off += (size_t)R_ * sizeof(int);        // 16 KB
  int* check_edges = (int*)(ws + off); off += (size_t)R_ * DC_ * sizeof(int);  // 96 KB

  hipMemsetAsync(counters, 0, (size_t)R_ * sizeof(int), stream);
  build_edges_kernel<<<(E_ + 255) / 256, 256, 0, stream>>>(edge_check, counters,
                                                           check_edges);
  sort_edges_kernel<<<(R_ + 255) / 256, 256, 0, stream>>>(check_edges);
  persistent_kernel<<<B_, THREADS_, 0, stream>>>(recv, check_edges, out);
}

// Round 10
// 246.564 us; speedup vs baseline: 5.0923x; 1.1801x over previous
//
#include <hip/hip_runtime.h>

// LDPC sum-product BP decode, (3,6)-regular, N=8192, R=4096, B=1024, 10 iters.
//
// R6: persistent-LDS — one workgroup per batch element, all state in LDS.
// R7: 1024 threads, prev-c2v state in registers (thread owns its 4 checks).
// R8 LESSON: never subtract near-equal large products; clamp BEFORE forming
// ratios so denominators stay strictly positive (sign-flip -> bit flip).
// R10: EXP-DOMAIN state. E_s[v] = e^{tot}, q_s[e] = e^{c2v}. Hot loop has
// ZERO exp/log: t = (E*hn - hd)*rcp(E*hn + hd) with (hn,hd)=(1-y,1+y) from
// own prev output (regs); y clamped +-0.999 FIRST (exact reference clip,
// R8-trap-safe: qd >= 0.001 > 0); q = (1+y)*rcp(1-y); var: E = e_llr*q0q1q2.
// exp once at init, log once at output. Check-edge VALU ~48 -> ~32 cyc.
// All ranges audited finite: E in [2e-15, 5e14], q in [5e-4, 1999]. No NaN.
//
// R2: deterministic edge table (atomic build + per-row sorting network).

#define N_  8192
#define R_  4096
#define DV_ 3
#define DC_ 6
#define E_  (N_ * DV_)
#define B_  1024
#define ITERS_ 10

#define THREADS_ 1024
#define CPT_ (R_ / THREADS_)   // 4 checks per thread
#define VPT_ (N_ / THREADS_)   // 8 variables per thread

#define LOG2E_ 1.442695041f
#define LN2_   0.69314718f

// Pass 1: scatter edges into per-check rows (slot order nondeterministic).
__global__ __launch_bounds__(256) void build_edges_kernel(
    const int* __restrict__ edge_check, int* __restrict__ counters,
    int* __restrict__ check_edges) {
  int e = blockIdx.x * 256 + threadIdx.x;
  if (e < E_) {
    int r = edge_check[e];
    int s = atomicAdd(&counters[r], 1);
    check_edges[r * DC_ + s] = e;
  }
}

// Pass 2: sort each 6-entry row ascending (optimal 12-comparator network).
// Makes the table deterministic regardless of atomic scheduling.
__global__ __launch_bounds__(256) void sort_edges_kernel(
    int* __restrict__ check_edges) {
  int r = blockIdx.x * 256 + threadIdx.x;
  if (r >= R_) return;
  int e0 = check_edges[r * DC_ + 0], e1 = check_edges[r * DC_ + 1];
  int e2 = check_edges[r * DC_ + 2], e3 = check_edges[r * DC_ + 3];
  int e4 = check_edges[r * DC_ + 4], e5 = check_edges[r * DC_ + 5];
#define CSWAP(a, b) { int lo = min(a, b), hi = max(a, b); a = lo; b = hi; }
  CSWAP(e0, e5) CSWAP(e1, e3) CSWAP(e2, e4)
  CSWAP(e1, e2) CSWAP(e3, e4)
  CSWAP(e0, e3) CSWAP(e2, e5)
  CSWAP(e0, e1) CSWAP(e2, e3) CSWAP(e4, e5)
  CSWAP(e1, e2) CSWAP(e3, e4)
#undef CSWAP
  check_edges[r * DC_ + 0] = e0; check_edges[r * DC_ + 1] = e1;
  check_edges[r * DC_ + 2] = e2; check_edges[r * DC_ + 3] = e3;
  check_edges[r * DC_ + 4] = e4; check_edges[r * DC_ + 5] = e5;
}

// Persistent exp-domain BP: block b decodes batch element b entirely in LDS.
// E_s[v] = e^{tot[v]}, q_s[e] = e^{c2v[e]}.
__global__ __launch_bounds__(THREADS_) void persistent_kernel(
    const float* __restrict__ recv, const int* __restrict__ check_edges,
    float* __restrict__ out) {
  __shared__ float q_s[E_];  // 96 KB, e^{c2v}, var-major (e = 3v+j)
  __shared__ float E_s[N_];  // 32 KB, e^{tot}
  const int b = blockIdx.x;
  const int tid = threadIdx.x;
  const float* r = recv + (size_t)b * N_;

  // This thread's 4 check rows -> registers, reused for all 10 iterations.
  int eidx[CPT_][DC_];
  int vidx[CPT_][DC_];
#pragma unroll
  for (int c = 0; c < CPT_; c++) {
    int rr = c * THREADS_ + tid;
#pragma unroll
    for (int i = 0; i < DC_; i++) {
      int e = check_edges[rr * DC_ + i];
      eidx[c][i] = e;
      vidx[c][i] = (int)((unsigned)e / 3u);  // edge_var[e] == e/3 by construction
    }
  }
  // (1-y, 1+y) of own previous c2v output; c2v=0 <=> y=0 <=> (1,1).
  float hn[CPT_][DC_], hd[CPT_][DC_];
#pragma unroll
  for (int c = 0; c < CPT_; c++)
#pragma unroll
    for (int i = 0; i < DC_; i++) { hn[c][i] = 1.0f; hd[c][i] = 1.0f; }

  // e^{llr} per owned var (llr = 2*recv); the only exps in the kernel.
  float e_llr[VPT_];
#pragma unroll
  for (int k = 0; k < VPT_; k++) {
    float llr = 2.0f * r[tid + k * THREADS_];
    e_llr[k] = __builtin_amdgcn_exp2f(llr * LOG2E_);
    E_s[tid + k * THREADS_] = e_llr[k];
  }
  __syncthreads();

  for (int iter = 0; iter < ITERS_; iter++) {
    // ---- check phase: no exp/log. t = tanh((tot - c2v_prev)/2) computed as
    // (E*hn - hd) / (E*hn + hd), since e^{tot-c2v} = E * (1-y)/(1+y). ----
#pragma unroll
    for (int c = 0; c < CPT_; c++) {
      float t[DC_];
#pragma unroll
      for (int i = 0; i < DC_; i++) {
        float A = E_s[vidx[c][i]] * hn[c][i];
        float num = A - hd[c][i];
        float den = A + hd[c][i];  // >= 0.001, strictly positive
        t[i] = num * __builtin_amdgcn_rcpf(den);
      }
      // leave-one-out products via prefix/suffix (division-free, |t|<=1+eps)
      float loo[DC_];
      float run = 1.0f;
#pragma unroll
      for (int i = 0; i < DC_; i++) { loo[i] = run; run *= t[i]; }
      run = 1.0f;
#pragma unroll
      for (int i = DC_ - 1; i >= 0; i--) { loo[i] *= run; run *= t[i]; }
#pragma unroll
      for (int i = 0; i < DC_; i++) {
        // clamp FIRST (reference clip semantics; keeps qd,qn >= 0.001 > 0)
        float y = loo[i];
        y = fminf(fmaxf(y, -0.999f), 0.999f);
        float qd = 1.0f - y;  // = hn_next (e^{-c2v} = qd/qn)
        float qn = 1.0f + y;  // = hd_next
        q_s[eidx[c][i]] = qn * __builtin_amdgcn_rcpf(qd);  // e^{c2v}
        hn[c][i] = qd;
        hd[c][i] = qn;
      }
    }
    __syncthreads();
    // ---- variable phase: E = e^{llr} * q0*q1*q2 (contiguous q reads) ----
#pragma unroll
    for (int k = 0; k < VPT_; k++) {
      int v = tid + k * THREADS_;
      E_s[v] = ((e_llr[k] * q_s[3 * v]) * q_s[3 * v + 1]) * q_s[3 * v + 2];
    }
    __syncthreads();
  }

  // ---- output: LLR = ln(E); bits = (LLR < 0); [B,N] layout ----
  const size_t BN = (size_t)B_ * N_;
#pragma unroll
  for (int k = 0; k < VPT_; k++) {
    int n = tid + k * THREADS_;
    float val = LN2_ * __builtin_amdgcn_logf(E_s[n]);  // E in [2e-15,5e14]
    out[(size_t)b * N_ + n] = val;
    out[BN + (size_t)b * N_ + n] = (val < 0.0f) ? 1.0f : 0.0f;
  }
}

extern "C" void kernel_launch(void* const* d_in, const int* in_sizes, int n_in,
                              void* d_out, int out_size, void* d_ws,
                              size_t ws_size, hipStream_t stream) {
  const float* recv = (const float*)d_in[0];     // [B, N]
  const int* edge_check = (const int*)d_in[2];   // [E]
  float* out = (float*)d_out;

  char* ws = (char*)d_ws;
  size_t off = 0;
  int* counters = (int*)(ws + off);    off += (size_t)R_ * sizeof(int);        // 16 KB
  int* check_edges = (int*)(ws + off); off += (size_t)R_ * DC_ * sizeof(int);  // 96 KB

  hipMemsetAsync(counters, 0, (size_t)R_ * sizeof(int), stream);
  build_edges_kernel<<<(E_ + 255) / 256, 256, 0, stream>>>(edge_check, counters,
                                                           check_edges);
  sort_edges_kernel<<<(R_ + 255) / 256, 256, 0, stream>>>(check_edges);
  persistent_kernel<<<B_, THREADS_, 0, stream>>>(recv, check_edges, out);
}